// Round 3
// baseline (470.012 us; speedup 1.0000x reference)
//
#include <hip/hip_runtime.h>

typedef unsigned short u16;
typedef unsigned int   u32;
typedef __attribute__((ext_vector_type(8))) short bf16x8;  // 8 bf16 in 4 VGPRs
typedef __attribute__((ext_vector_type(4))) float f32x4;

#define LL 384
#define DP 128
#define SZROW ((size_t)LL * LL)   // 147456

// XOR-swizzled LDS tile addressing (128 bf16 per row, 16B groups) -> 2-way max
// bank aliasing on both row-wise writes and B-fragment (column-of-rows) reads.
#define SWZ(row, col) (((row) << 7) + (((((col) >> 3) ^ ((row) & 7)) << 3) | ((col) & 7)))

__device__ __forceinline__ u16 f2bf(float x) {
  u32 u = __builtin_bit_cast(u32, x);
  u = (u + 0x7FFFu + ((u >> 16) & 1u)) >> 16;   // RNE
  return (u16)u;
}
__device__ __forceinline__ float bf2f(u16 h) {
  return __builtin_bit_cast(float, ((u32)h) << 16);
}
__device__ __forceinline__ uint2 pack4(float a, float b, float c, float d) {
  uint2 p;
  p.x = (u32)f2bf(a) | ((u32)f2bf(b) << 16);
  p.y = (u32)f2bf(c) | ((u32)f2bf(d) << 16);
  return p;
}

// ---------------------------------------------------------------------------
// K0: weight prep. Wt[out][in] = W[in][out] * scale, bf16.
// m: 0=Wq(*1/sqrt(32)) 1=Wk(*1/384) 2=Wv 3=Wg 4=Wout
// ---------------------------------------------------------------------------
__global__ void k_prep(const float* __restrict__ Wq, const float* __restrict__ Wk,
                       const float* __restrict__ Wv, const float* __restrict__ Wg,
                       const float* __restrict__ Wout, u16* __restrict__ wbf) {
  int r = blockIdx.x, c = threadIdx.x, m = blockIdx.y;
  const float* W;
  float s = 1.0f;
  if (m == 0)      { W = Wq;  s = 0.17677669529663687f; }
  else if (m == 1) { W = Wk;  s = 1.0f / 384.0f; }
  else if (m == 2) { W = Wv; }
  else if (m == 3) { W = Wg; }
  else             { W = Wout; }
  wbf[m * DP * DP + r * DP + c] = f2bf(W[c * DP + r] * s);
}

// ---------------------------------------------------------------------------
// Wave-level GEMM: D[m][i] = sum_k A[m][k] * tile[i][k]   (D = W . tile^T)
// M = 32 rows (this wave), N = NS*16 i-rows, K = 128.
// mfma_f32_16x16x32_bf16 frags:
//   A-frag: A[m = lane&15][k = (lane>>4)*8 + j]
//   B-frag: B[k = (lane>>4)*8 + j][n = lane&15]
//   D:      D[row = (lane>>4)*4 + reg][col = lane&15]
// ---------------------------------------------------------------------------
template <int NS>
__device__ __forceinline__ void wave_gemm(const u16* __restrict__ W, const u16* pnl,
                                          int wave, int q, int r, f32x4 (&acc)[2][NS]) {
  const f32x4 FZ = {0.f, 0.f, 0.f, 0.f};
#pragma unroll
  for (int ms = 0; ms < 2; ++ms)
#pragma unroll
    for (int ns = 0; ns < NS; ++ns) acc[ms][ns] = FZ;
#pragma unroll
  for (int kc = 0; kc < 4; ++kc) {
    bf16x8 a0 = *(const bf16x8*)(W + (wave * 32 + r) * DP + kc * 32 + q * 8);
    bf16x8 a1 = *(const bf16x8*)(W + (wave * 32 + 16 + r) * DP + kc * 32 + q * 8);
#pragma unroll
    for (int ns = 0; ns < NS; ++ns) {
      bf16x8 b = *(const bf16x8*)(pnl + SWZ(ns * 16 + r, kc * 32 + q * 8));
      acc[0][ns] = __builtin_amdgcn_mfma_f32_16x16x32_bf16(a0, b, acc[0][ns], 0, 0, 0);
      acc[1][ns] = __builtin_amdgcn_mfma_f32_16x16x32_bf16(a1, b, acc[1][ns], 0, 0, 0);
    }
  }
}

// ---------------------------------------------------------------------------
// K1: LN(pair_t) + 4 projections. Block = (ib, n): 64 i-rows of the (n,i)
// plane. pn[i][:] = LN(pair[i][n][:]).
// Outputs: Q/K as [n][i][128] bf16; V and G transposed: [n][c][i] bf16
// (via padded LDS transpose tile -> fully vectorized 16B/lane stores).
// ---------------------------------------------------------------------------
__global__ __launch_bounds__(256) void k1_ln_proj(
    const float* __restrict__ pair, const float* __restrict__ gamma_p,
    const float* __restrict__ beta_p, const u16* __restrict__ wbf,
    const float* __restrict__ bg, u16* __restrict__ Qb, u16* __restrict__ Kb,
    u16* __restrict__ Vtb, u16* __restrict__ Gtb) {
  __shared__ u16 pn[64 * 128];   // swizzled LN tile
  __shared__ u16 T[128 * 72];    // padded transpose staging tile
  const int ib = blockIdx.x, n = blockIdx.y;
  const int tid = threadIdx.x;
  const int lane = tid & 63, wave = tid >> 6;
  const int q = lane >> 4, r = lane & 15;
  const int l32 = lane & 31, half = lane >> 5;
  const int c0 = l32 * 4;
  const float4 gm = *(const float4*)(gamma_p + c0);
  const float4 bt = *(const float4*)(beta_p + c0);

  // ---- LN: 2 rows/wave/iter, 32 lanes x float4 per row ----
#pragma unroll
  for (int it = 0; it < 8; ++it) {
    const int il = it * 8 + wave * 2 + half;
    const float* rowp = pair + ((size_t)(ib * 64 + il) * LL + n) * DP + c0;
    float4 x = *(const float4*)rowp;
    float s1 = x.x + x.y + x.z + x.w;
    float s2 = x.x * x.x + x.y * x.y + x.z * x.z + x.w * x.w;
#pragma unroll
    for (int m = 16; m >= 1; m >>= 1) { s1 += __shfl_xor(s1, m); s2 += __shfl_xor(s2, m); }
    float mean = s1 * (1.0f / 128.0f);
    float rs = rsqrtf(s2 * (1.0f / 128.0f) - mean * mean + 1e-5f);
    *(uint2*)(&pn[SWZ(il, c0)]) =
        pack4((x.x - mean) * rs * gm.x + bt.x, (x.y - mean) * rs * gm.y + bt.y,
              (x.z - mean) * rs * gm.z + bt.z, (x.w - mean) * rs * gm.w + bt.w);
  }
  __syncthreads();

  f32x4 acc[2][4];

  // ---- Q ----
  wave_gemm<4>(wbf, pn, wave, q, r, acc);
#pragma unroll
  for (int ms = 0; ms < 2; ++ms) {
    int ob = wave * 32 + ms * 16 + q * 4;
#pragma unroll
    for (int ns = 0; ns < 4; ++ns) {
      size_t base = ((size_t)n * LL + ib * 64 + ns * 16 + r) * DP + ob;
      *(uint2*)(Qb + base) = pack4(acc[ms][ns][0], acc[ms][ns][1], acc[ms][ns][2], acc[ms][ns][3]);
    }
  }
  // ---- K ----
  wave_gemm<4>(wbf + DP * DP, pn, wave, q, r, acc);
#pragma unroll
  for (int ms = 0; ms < 2; ++ms) {
    int ob = wave * 32 + ms * 16 + q * 4;
#pragma unroll
    for (int ns = 0; ns < 4; ++ns) {
      size_t base = ((size_t)n * LL + ib * 64 + ns * 16 + r) * DP + ob;
      *(uint2*)(Kb + base) = pack4(acc[ms][ns][0], acc[ms][ns][1], acc[ms][ns][2], acc[ms][ns][3]);
    }
  }
  // ---- V: transpose via T, coalesced store Vt[n][c][i] ----
  wave_gemm<4>(wbf + 2 * DP * DP, pn, wave, q, r, acc);
#pragma unroll
  for (int ms = 0; ms < 2; ++ms)
#pragma unroll
    for (int ns = 0; ns < 4; ++ns)
#pragma unroll
      for (int reg = 0; reg < 4; ++reg)
        T[(wave * 32 + ms * 16 + q * 4 + reg) * 72 + ns * 16 + r] = f2bf(acc[ms][ns][reg]);
  __syncthreads();
#pragma unroll
  for (int it = 0; it < 4; ++it) {
    int c = it * 32 + (tid >> 3);
    int il2 = (tid & 7) * 8;
    *(uint4*)(Vtb + ((size_t)n * DP + c) * LL + ib * 64 + il2) =
        *(const uint4*)(T + c * 72 + il2);
  }
  // ---- G = sigmoid(pn@Wg + bg): transpose via T, store Gt[n][c][i] ----
  wave_gemm<4>(wbf + 3 * DP * DP, pn, wave, q, r, acc);
  __syncthreads();   // all V coop-reads of T done before overwrite
#pragma unroll
  for (int ms = 0; ms < 2; ++ms) {
    f32x4 bgv = *(const f32x4*)(bg + wave * 32 + ms * 16 + q * 4);
#pragma unroll
    for (int ns = 0; ns < 4; ++ns)
#pragma unroll
      for (int reg = 0; reg < 4; ++reg) {
        float x = acc[ms][ns][reg] + bgv[reg];
        T[(wave * 32 + ms * 16 + q * 4 + reg) * 72 + ns * 16 + r] =
            f2bf(1.0f / (1.0f + __expf(-x)));
      }
  }
  __syncthreads();
#pragma unroll
  for (int it = 0; it < 4; ++it) {
    int c = it * 32 + (tid >> 3);
    int il2 = (tid & 7) * 8;
    *(uint4*)(Gtb + ((size_t)n * DP + c) * LL + ib * 64 + il2) =
        *(const uint4*)(T + c * 72 + il2);
  }
}

// ---------------------------------------------------------------------------
// K2a: bias-LN logit plane. part[(32+h)][i][j] = LN(bias[j][i][:]) . Wb[:,h]
// 2 rows/wave (32 lanes x float4 each), fp32 throughout.
// ---------------------------------------------------------------------------
__global__ __launch_bounds__(256) void k2a_bias(
    const float* __restrict__ bias, const float* __restrict__ gamma_b,
    const float* __restrict__ beta_b, const float* __restrict__ Wb,
    float* __restrict__ part) {
  const int lane = threadIdx.x & 63, wave = threadIdx.x >> 6;
  const int l32 = lane & 31, half = lane >> 5;
  const int row = blockIdx.x * 8 + wave * 2 + half;
  const int i = row % LL, j = row / LL;
  const int c0 = l32 * 4;
  float4 x = *(const float4*)(bias + (size_t)row * DP + c0);
  float s1 = x.x + x.y + x.z + x.w;
  float s2 = x.x * x.x + x.y * x.y + x.z * x.z + x.w * x.w;
#pragma unroll
  for (int m = 16; m >= 1; m >>= 1) { s1 += __shfl_xor(s1, m); s2 += __shfl_xor(s2, m); }
  float mean = s1 * (1.0f / 128.0f);
  float rs = rsqrtf(s2 * (1.0f / 128.0f) - mean * mean + 1e-5f);
  const float4 gm = *(const float4*)(gamma_b + c0);
  const float4 bt = *(const float4*)(beta_b + c0);
  float y0 = (x.x - mean) * rs * gm.x + bt.x;
  float y1 = (x.y - mean) * rs * gm.y + bt.y;
  float y2 = (x.z - mean) * rs * gm.z + bt.z;
  float y3 = (x.w - mean) * rs * gm.w + bt.w;
  f32x4 w0 = *(const f32x4*)(Wb + (c0 + 0) * 4);
  f32x4 w1 = *(const f32x4*)(Wb + (c0 + 1) * 4);
  f32x4 w2 = *(const f32x4*)(Wb + (c0 + 2) * 4);
  f32x4 w3 = *(const f32x4*)(Wb + (c0 + 3) * 4);
  f32x4 pv = y0 * w0 + y1 * w1 + y2 * w2 + y3 * w3;
#pragma unroll
  for (int m = 16; m >= 1; m >>= 1) {
    pv[0] += __shfl_xor(pv[0], m); pv[1] += __shfl_xor(pv[1], m);
    pv[2] += __shfl_xor(pv[2], m); pv[3] += __shfl_xor(pv[3], m);
  }
  if (l32 == 0) {
    size_t o = (size_t)i * LL + j;
    part[(size_t)32 * SZROW + o] = pv[0];
    part[(size_t)33 * SZROW + o] = pv[1];
    part[(size_t)34 * SZROW + o] = pv[2];
    part[(size_t)35 * SZROW + o] = pv[3];
  }
}

// ---------------------------------------------------------------------------
// K2b: attn_h[i][j] += sum_{n in chunk, k} Q[n][i][h,k] K[n][j][h,k]
// Grid (x = jt*8+nc [64], y = it [8]); 48x48 tile; wave = head. Split-K
// partials to part[nc*4+h]. linear_id % 8 == nc for both the K-slice
// (jt,nc) and Q-slice (it,nc) sharers -> XCD-local L2 reuse.
// ---------------------------------------------------------------------------
__global__ __launch_bounds__(256) void k2b_qk(const u16* __restrict__ Qb,
                                              const u16* __restrict__ Kb,
                                              float* __restrict__ part) {
  const int it = blockIdx.y, jt = blockIdx.x >> 3, nc = blockIdx.x & 7;
  const int lane = threadIdx.x & 63, h = threadIdx.x >> 6;
  const int q = lane >> 4, r = lane & 15;
  const f32x4 FZ = {0.f, 0.f, 0.f, 0.f};
  f32x4 acc[3][3];
#pragma unroll
  for (int a = 0; a < 3; ++a)
#pragma unroll
    for (int b = 0; b < 3; ++b) acc[a][b] = FZ;
  const int coff = h * 32 + q * 8;
#pragma unroll 2
  for (int n = nc * 48; n < nc * 48 + 48; ++n) {
    const u16* Qp = Qb + ((size_t)n * LL + it * 48) * DP + coff;
    const u16* Kp = Kb + ((size_t)n * LL + jt * 48) * DP + coff;
    bf16x8 av[3], bv[3];
#pragma unroll
    for (int s = 0; s < 3; ++s) {
      av[s] = *(const bf16x8*)(Qp + (s * 16 + r) * DP);
      bv[s] = *(const bf16x8*)(Kp + (s * 16 + r) * DP);
    }
#pragma unroll
    for (int is = 0; is < 3; ++is)
#pragma unroll
      for (int js = 0; js < 3; ++js)
        acc[is][js] = __builtin_amdgcn_mfma_f32_16x16x32_bf16(av[is], bv[js], acc[is][js], 0, 0, 0);
  }
  float* dst = part + (size_t)(nc * 4 + h) * SZROW;
#pragma unroll
  for (int is = 0; is < 3; ++is)
#pragma unroll
    for (int js = 0; js < 3; ++js)
#pragma unroll
      for (int reg = 0; reg < 4; ++reg)
        dst[(size_t)(it * 48 + is * 16 + q * 4 + reg) * LL + jt * 48 + js * 16 + r] =
            acc[is][js][reg];
}

// ---------------------------------------------------------------------------
// K3: logits = sum of 9 partial planes; softmax over j; a -> bf16 [h][i][j].
// ---------------------------------------------------------------------------
__global__ __launch_bounds__(384) void k3_softmax(const float* __restrict__ part,
                                                  u16* __restrict__ abf) {
  const int i = blockIdx.x, h = blockIdx.y, j = threadIdx.x;
  __shared__ float red[6];
  float l = 0.f;
#pragma unroll
  for (int c = 0; c < 9; ++c) l += part[(size_t)(c * 4 + h) * SZROW + (size_t)i * LL + j];
  float m = l;
#pragma unroll
  for (int s = 32; s >= 1; s >>= 1) m = fmaxf(m, __shfl_xor(m, s));
  const int wv = threadIdx.x >> 6;
  if ((threadIdx.x & 63) == 0) red[wv] = m;
  __syncthreads();
  m = fmaxf(fmaxf(fmaxf(red[0], red[1]), fmaxf(red[2], red[3])), fmaxf(red[4], red[5]));
  float e = __expf(l - m);
  float s = e;
#pragma unroll
  for (int t = 32; t >= 1; t >>= 1) s += __shfl_xor(s, t);
  __syncthreads();
  if ((threadIdx.x & 63) == 0) red[wv] = s;
  __syncthreads();
  s = red[0] + red[1] + red[2] + red[3] + red[4] + red[5];
  abf[((size_t)h * LL + i) * LL + j] = f2bf(e / s);
}

// ---------------------------------------------------------------------------
// K4: O[n][i][h,d] = sum_j a_h[i][j] V[n][j][h,d]; gate; @Wout + bout;
// store transposed: out[i][n][:]. Grid x = n (so the 6 ib-blocks sharing
// Vt[n] land on ONE XCD: ids differ by 384 = 0 mod 8), y = ib; wave = head.
// Vt B-fragments preloaded into registers in two batches of 12 dwordx4
// loads -> kc-loop is 4 a-loads per 8 MFMAs.
// ---------------------------------------------------------------------------
__global__ __launch_bounds__(256) void k4_out(
    const u16* __restrict__ abf, const u16* __restrict__ Vtb,
    const u16* __restrict__ Gtb, const u16* __restrict__ Wot,
    const float* __restrict__ bout, float* __restrict__ out) {
  __shared__ u16 go[64 * 128];
  const int n = blockIdx.x, ib = blockIdx.y;
  const int lane = threadIdx.x & 63, wave = threadIdx.x >> 6;
  const int h = wave;
  const int q = lane >> 4, r = lane & 15;

  // hoisted gate loads (independent of the PV loop)
  uint2 gp[4][2];
#pragma unroll
  for (int is = 0; is < 4; ++is)
#pragma unroll
    for (int ds = 0; ds < 2; ++ds) {
      int c = h * 32 + ds * 16 + r;
      gp[is][ds] =
          *(const uint2*)(Gtb + ((size_t)n * DP + c) * LL + ib * 64 + is * 16 + q * 4);
    }

  const f32x4 FZ = {0.f, 0.f, 0.f, 0.f};
  f32x4 acc[4][2];
#pragma unroll
  for (int is = 0; is < 4; ++is) { acc[is][0] = FZ; acc[is][1] = FZ; }

  const u16* Vbase = Vtb + ((size_t)n * DP + h * 32) * LL;
  const u16* Abase = abf + ((size_t)h * LL + ib * 64) * LL;
#pragma unroll
  for (int halfk = 0; halfk < 2; ++halfk) {
    bf16x8 vb[6][2];
#pragma unroll
    for (int k2 = 0; k2 < 6; ++k2) {
      const u16* Vp = Vbase + (halfk * 6 + k2) * 32 + q * 8;
      vb[k2][0] = *(const bf16x8*)(Vp + (size_t)r * LL);
      vb[k2][1] = *(const bf16x8*)(Vp + (size_t)(16 + r) * LL);
    }
#pragma unroll
    for (int k2 = 0; k2 < 6; ++k2) {
      const int kc = halfk * 6 + k2;
#pragma unroll
      for (int is = 0; is < 4; ++is) {
        bf16x8 a = *(const bf16x8*)(Abase + (size_t)(is * 16 + r) * LL + kc * 32 + q * 8);
        acc[is][0] = __builtin_amdgcn_mfma_f32_16x16x32_bf16(a, vb[k2][0], acc[is][0], 0, 0, 0);
        acc[is][1] = __builtin_amdgcn_mfma_f32_16x16x32_bf16(a, vb[k2][1], acc[is][1], 0, 0, 0);
      }
    }
  }
  // gate + stash go (bf16) in swizzled LDS
#pragma unroll
  for (int is = 0; is < 4; ++is)
#pragma unroll
    for (int ds = 0; ds < 2; ++ds) {
      int c = h * 32 + ds * 16 + r;
      float g0 = bf2f((u16)(gp[is][ds].x & 0xffff)), g1 = bf2f((u16)(gp[is][ds].x >> 16));
      float g2 = bf2f((u16)(gp[is][ds].y & 0xffff)), g3 = bf2f((u16)(gp[is][ds].y >> 16));
      int il = is * 16 + q * 4;
      go[SWZ(il + 0, c)] = f2bf(g0 * acc[is][ds][0]);
      go[SWZ(il + 1, c)] = f2bf(g1 * acc[is][ds][1]);
      go[SWZ(il + 2, c)] = f2bf(g2 * acc[is][ds][2]);
      go[SWZ(il + 3, c)] = f2bf(g3 * acc[is][ds][3]);
    }
  __syncthreads();

  // out[i][co] = go[i][:] @ Wout ; computed as D[co][i] so co is reg-contig.
  f32x4 acc2[2][4];
  wave_gemm<4>(Wot, go, wave, q, r, acc2);
#pragma unroll
  for (int ms = 0; ms < 2; ++ms) {
    int co = wave * 32 + ms * 16 + q * 4;
    f32x4 bo = *(const f32x4*)(bout + co);
#pragma unroll
    for (int ns = 0; ns < 4; ++ns) {
      f32x4 v = acc2[ms][ns] + bo;
      *(f32x4*)(out + ((size_t)(ib * 64 + ns * 16 + r) * LL + n) * DP + co) = v;
    }
  }
}

// ---------------------------------------------------------------------------
extern "C" void kernel_launch(void* const* d_in, const int* in_sizes, int n_in,
                              void* d_out, int out_size, void* d_ws, size_t ws_size,
                              hipStream_t stream) {
  const float* pair    = (const float*)d_in[0];
  const float* bias    = (const float*)d_in[1];
  const float* gamma_p = (const float*)d_in[2];
  const float* beta_p  = (const float*)d_in[3];
  const float* gamma_b = (const float*)d_in[4];
  const float* beta_b  = (const float*)d_in[5];
  const float* Wq      = (const float*)d_in[6];
  const float* Wk      = (const float*)d_in[7];
  const float* Wv      = (const float*)d_in[8];
  const float* Wb      = (const float*)d_in[9];
  const float* Wg      = (const float*)d_in[10];
  const float* bg      = (const float*)d_in[11];
  const float* Wout    = (const float*)d_in[12];
  const float* bout    = (const float*)d_in[13];

  // Q,K (bf16) live inside d_out (2 * L*L*128 u16 == out_size * 4 bytes);
  // fully consumed by k2b before k4 overwrites d_out with the result.
  u16* Qb = (u16*)d_out;
  u16* Kb = Qb + (size_t)LL * LL * DP;

  char* ws = (char*)d_ws;
  const size_t BF_PLANE = (size_t)LL * LL * DP * 2;  // 37748736 B
  u16*   Vtb  = (u16*)ws;
  u16*   Gtb  = (u16*)(ws + BF_PLANE);
  float* part = (float*)(ws + 2 * BF_PLANE);                     // 36 planes fp32
  u16*   abf  = (u16*)(ws + 2 * BF_PLANE + 36 * SZROW * 4);
  u16*   wbf  = (u16*)(ws + 2 * BF_PLANE + 36 * SZROW * 4 + 4 * SZROW * 2);
  float* out  = (float*)d_out;

  k_prep<<<dim3(128, 5), 128, 0, stream>>>(Wq, Wk, Wv, Wg, Wout, wbf);
  k1_ln_proj<<<dim3(6, 384), 256, 0, stream>>>(pair, gamma_p, beta_p, wbf, bg, Qb, Kb, Vtb, Gtb);
  k2a_bias<<<dim3(18432), 256, 0, stream>>>(bias, gamma_b, beta_b, Wb, part);
  k2b_qk<<<dim3(64, 8), 256, 0, stream>>>(Qb, Kb, part);
  k3_softmax<<<dim3(384, 4), 384, 0, stream>>>(part, abf);
  k4_out<<<dim3(384, 6), 256, 0, stream>>>(abf, Vtb, Gtb, wbf + 4 * DP * DP, bout, out);
}

// Round 4
// 395.870 us; speedup vs baseline: 1.1873x; 1.1873x over previous
//
#include <hip/hip_runtime.h>

typedef unsigned short u16;
typedef unsigned int   u32;
typedef __attribute__((ext_vector_type(8))) short bf16x8;  // 8 bf16 in 4 VGPRs
typedef __attribute__((ext_vector_type(4))) float f32x4;

#define LL 384
#define DP 128
#define SZROW ((size_t)LL * LL)   // 147456

// XOR-swizzled LDS tile addressing (128 bf16 per row, 16B groups) -> 2-way max
// bank aliasing on both row-wise writes and B-fragment (column-of-rows) reads.
#define SWZ(row, col) (((row) << 7) + (((((col) >> 3) ^ ((row) & 7)) << 3) | ((col) & 7)))

__device__ __forceinline__ u16 f2bf(float x) {
  u32 u = __builtin_bit_cast(u32, x);
  u = (u + 0x7FFFu + ((u >> 16) & 1u)) >> 16;   // RNE
  return (u16)u;
}
__device__ __forceinline__ float bf2f(u16 h) {
  return __builtin_bit_cast(float, ((u32)h) << 16);
}
__device__ __forceinline__ uint2 pack4(float a, float b, float c, float d) {
  uint2 p;
  p.x = (u32)f2bf(a) | ((u32)f2bf(b) << 16);
  p.y = (u32)f2bf(c) | ((u32)f2bf(d) << 16);
  return p;
}

// ---------------------------------------------------------------------------
// Blocked layouts (all derived to make consumer loads contiguous-1KB/inst):
//   Q_p/K_p [n][h(4)][i(384)][c%32(32)]   c-block kq == h (32 ch per head)
//   V_p     [n][kc(12)][c(128)][j%32(32)]  kc = j/32
//   a_p     [h][kc(12)][i(384)][j%32(32)]
//   Gt      [n][c(128)][i(384)]            (unchanged)
// ---------------------------------------------------------------------------

// ---------------------------------------------------------------------------
// K0: weight prep. Wt[out][in] = W[in][out] * scale, bf16.
// ---------------------------------------------------------------------------
__global__ void k_prep(const float* __restrict__ Wq, const float* __restrict__ Wk,
                       const float* __restrict__ Wv, const float* __restrict__ Wg,
                       const float* __restrict__ Wout, u16* __restrict__ wbf) {
  int r = blockIdx.x, c = threadIdx.x, m = blockIdx.y;
  const float* W;
  float s = 1.0f;
  if (m == 0)      { W = Wq;  s = 0.17677669529663687f; }
  else if (m == 1) { W = Wk;  s = 1.0f / 384.0f; }
  else if (m == 2) { W = Wv; }
  else if (m == 3) { W = Wg; }
  else             { W = Wout; }
  wbf[m * DP * DP + r * DP + c] = f2bf(W[c * DP + r] * s);
}

// ---------------------------------------------------------------------------
// Wave-level GEMM: D[m][i] = sum_k A[m][k] * tile[i][k]   (D = W . tile^T)
// mfma_f32_16x16x32_bf16 frags:
//   A-frag: A[m = lane&15][k = (lane>>4)*8 + j]
//   B-frag: B[k = (lane>>4)*8 + j][n = lane&15]
//   D:      D[row = (lane>>4)*4 + reg][col = lane&15]
// ---------------------------------------------------------------------------
template <int NS>
__device__ __forceinline__ void wave_gemm(const u16* __restrict__ W, const u16* pnl,
                                          int wave, int q, int r, f32x4 (&acc)[2][NS]) {
  const f32x4 FZ = {0.f, 0.f, 0.f, 0.f};
#pragma unroll
  for (int ms = 0; ms < 2; ++ms)
#pragma unroll
    for (int ns = 0; ns < NS; ++ns) acc[ms][ns] = FZ;
#pragma unroll
  for (int kc = 0; kc < 4; ++kc) {
    bf16x8 a0 = *(const bf16x8*)(W + (wave * 32 + r) * DP + kc * 32 + q * 8);
    bf16x8 a1 = *(const bf16x8*)(W + (wave * 32 + 16 + r) * DP + kc * 32 + q * 8);
#pragma unroll
    for (int ns = 0; ns < NS; ++ns) {
      bf16x8 b = *(const bf16x8*)(pnl + SWZ(ns * 16 + r, kc * 32 + q * 8));
      acc[0][ns] = __builtin_amdgcn_mfma_f32_16x16x32_bf16(a0, b, acc[0][ns], 0, 0, 0);
      acc[1][ns] = __builtin_amdgcn_mfma_f32_16x16x32_bf16(a1, b, acc[1][ns], 0, 0, 0);
    }
  }
}

// ---------------------------------------------------------------------------
// K1: LN(pair_t) + 4 projections. Block = (ib, n): 64 i-rows of the (n,i)
// plane. pn[i][:] = LN(pair[i][n][:]).
// Outputs: Q_p/K_p blocked; V_p blocked (via T, fully coalesced); Gt[n][c][i].
// ---------------------------------------------------------------------------
__global__ __launch_bounds__(256) void k1_ln_proj(
    const float* __restrict__ pair, const float* __restrict__ gamma_p,
    const float* __restrict__ beta_p, const u16* __restrict__ wbf,
    const float* __restrict__ bg, u16* __restrict__ Qb, u16* __restrict__ Kb,
    u16* __restrict__ Vp, u16* __restrict__ Gtb) {
  __shared__ u16 pn[64 * 128];   // swizzled LN tile
  __shared__ u16 T[128 * 72];    // padded transpose staging tile
  const int ib = blockIdx.x, n = blockIdx.y;
  const int tid = threadIdx.x;
  const int lane = tid & 63, wave = tid >> 6;
  const int q = lane >> 4, r = lane & 15;
  const int l32 = lane & 31, half = lane >> 5;
  const int c0 = l32 * 4;
  const float4 gm = *(const float4*)(gamma_p + c0);
  const float4 bt = *(const float4*)(beta_p + c0);

  // ---- LN: 2 rows/wave/iter, 32 lanes x float4 per row ----
#pragma unroll
  for (int it = 0; it < 8; ++it) {
    const int il = it * 8 + wave * 2 + half;
    const float* rowp = pair + ((size_t)(ib * 64 + il) * LL + n) * DP + c0;
    float4 x = *(const float4*)rowp;
    float s1 = x.x + x.y + x.z + x.w;
    float s2 = x.x * x.x + x.y * x.y + x.z * x.z + x.w * x.w;
#pragma unroll
    for (int m = 16; m >= 1; m >>= 1) { s1 += __shfl_xor(s1, m); s2 += __shfl_xor(s2, m); }
    float mean = s1 * (1.0f / 128.0f);
    float rs = rsqrtf(s2 * (1.0f / 128.0f) - mean * mean + 1e-5f);
    *(uint2*)(&pn[SWZ(il, c0)]) =
        pack4((x.x - mean) * rs * gm.x + bt.x, (x.y - mean) * rs * gm.y + bt.y,
              (x.z - mean) * rs * gm.z + bt.z, (x.w - mean) * rs * gm.w + bt.w);
  }
  __syncthreads();

  f32x4 acc[2][4];

  // ---- Q: store blocked Q_p[n][kq=wave][i][c%32] ----
  wave_gemm<4>(wbf, pn, wave, q, r, acc);
#pragma unroll
  for (int ms = 0; ms < 2; ++ms) {
#pragma unroll
    for (int ns = 0; ns < 4; ++ns) {
      size_t base = (((size_t)n * 4 + wave) * LL + ib * 64 + ns * 16 + r) * 32 + ms * 16 + q * 4;
      *(uint2*)(Qb + base) = pack4(acc[ms][ns][0], acc[ms][ns][1], acc[ms][ns][2], acc[ms][ns][3]);
    }
  }
  // ---- K ----
  wave_gemm<4>(wbf + DP * DP, pn, wave, q, r, acc);
#pragma unroll
  for (int ms = 0; ms < 2; ++ms) {
#pragma unroll
    for (int ns = 0; ns < 4; ++ns) {
      size_t base = (((size_t)n * 4 + wave) * LL + ib * 64 + ns * 16 + r) * 32 + ms * 16 + q * 4;
      *(uint2*)(Kb + base) = pack4(acc[ms][ns][0], acc[ms][ns][1], acc[ms][ns][2], acc[ms][ns][3]);
    }
  }
  // ---- V: transpose via T, store blocked V_p[n][kc][c][j%32], coalesced ----
  wave_gemm<4>(wbf + 2 * DP * DP, pn, wave, q, r, acc);
#pragma unroll
  for (int ms = 0; ms < 2; ++ms)
#pragma unroll
    for (int ns = 0; ns < 4; ++ns)
#pragma unroll
      for (int reg = 0; reg < 4; ++reg)
        T[(wave * 32 + ms * 16 + q * 4 + reg) * 72 + ns * 16 + r] = f2bf(acc[ms][ns][reg]);
  __syncthreads();
#pragma unroll
  for (int kk = 0; kk < 2; ++kk) {
    u16* dst = Vp + ((size_t)n * 12 + ib * 2 + kk) * (128 * 32);
#pragma unroll
    for (int e = 0; e < 2; ++e) {
      int m = e * 256 + tid;              // 512 chunks of 16B per kk-plane
      int c = m >> 2, io = (m & 3) * 8;
      *(uint4*)(dst + c * 32 + io) = *(const uint4*)(T + c * 72 + kk * 32 + io);
    }
  }
  // ---- G = sigmoid(pn@Wg + bg): transpose via T, store Gt[n][c][i] ----
  wave_gemm<4>(wbf + 3 * DP * DP, pn, wave, q, r, acc);
  __syncthreads();   // all V coop-reads of T done before overwrite
#pragma unroll
  for (int ms = 0; ms < 2; ++ms) {
    f32x4 bgv = *(const f32x4*)(bg + wave * 32 + ms * 16 + q * 4);
#pragma unroll
    for (int ns = 0; ns < 4; ++ns)
#pragma unroll
      for (int reg = 0; reg < 4; ++reg) {
        float x = acc[ms][ns][reg] + bgv[reg];
        T[(wave * 32 + ms * 16 + q * 4 + reg) * 72 + ns * 16 + r] =
            f2bf(1.0f / (1.0f + __expf(-x)));
      }
  }
  __syncthreads();
#pragma unroll
  for (int it = 0; it < 4; ++it) {
    int c = it * 32 + (tid >> 3);
    int il2 = (tid & 7) * 8;
    *(uint4*)(Gtb + ((size_t)n * DP + c) * LL + ib * 64 + il2) =
        *(const uint4*)(T + c * 72 + il2);
  }
}

// ---------------------------------------------------------------------------
// K2a: bias-LN logit plane. part[(32+h)][i][j] = LN(bias[j][i][:]) . Wb[:,h]
// ---------------------------------------------------------------------------
__global__ __launch_bounds__(256) void k2a_bias(
    const float* __restrict__ bias, const float* __restrict__ gamma_b,
    const float* __restrict__ beta_b, const float* __restrict__ Wb,
    float* __restrict__ part) {
  const int lane = threadIdx.x & 63, wave = threadIdx.x >> 6;
  const int l32 = lane & 31, half = lane >> 5;
  const int row = blockIdx.x * 8 + wave * 2 + half;
  const int i = row % LL, j = row / LL;
  const int c0 = l32 * 4;
  float4 x = *(const float4*)(bias + (size_t)row * DP + c0);
  float s1 = x.x + x.y + x.z + x.w;
  float s2 = x.x * x.x + x.y * x.y + x.z * x.z + x.w * x.w;
#pragma unroll
  for (int m = 16; m >= 1; m >>= 1) { s1 += __shfl_xor(s1, m); s2 += __shfl_xor(s2, m); }
  float mean = s1 * (1.0f / 128.0f);
  float rs = rsqrtf(s2 * (1.0f / 128.0f) - mean * mean + 1e-5f);
  const float4 gm = *(const float4*)(gamma_b + c0);
  const float4 bt = *(const float4*)(beta_b + c0);
  float y0 = (x.x - mean) * rs * gm.x + bt.x;
  float y1 = (x.y - mean) * rs * gm.y + bt.y;
  float y2 = (x.z - mean) * rs * gm.z + bt.z;
  float y3 = (x.w - mean) * rs * gm.w + bt.w;
  f32x4 w0 = *(const f32x4*)(Wb + (c0 + 0) * 4);
  f32x4 w1 = *(const f32x4*)(Wb + (c0 + 1) * 4);
  f32x4 w2 = *(const f32x4*)(Wb + (c0 + 2) * 4);
  f32x4 w3 = *(const f32x4*)(Wb + (c0 + 3) * 4);
  f32x4 pv = y0 * w0 + y1 * w1 + y2 * w2 + y3 * w3;
#pragma unroll
  for (int m = 16; m >= 1; m >>= 1) {
    pv[0] += __shfl_xor(pv[0], m); pv[1] += __shfl_xor(pv[1], m);
    pv[2] += __shfl_xor(pv[2], m); pv[3] += __shfl_xor(pv[3], m);
  }
  if (l32 == 0) {
    size_t o = (size_t)i * LL + j;
    part[(size_t)32 * SZROW + o] = pv[0];
    part[(size_t)33 * SZROW + o] = pv[1];
    part[(size_t)34 * SZROW + o] = pv[2];
    part[(size_t)35 * SZROW + o] = pv[3];
  }
}

// ---------------------------------------------------------------------------
// K2b: attn_h[i][j] += sum_{n in chunk} Q[n][i][h:] . K[n][j][h:]
// Grid (x = jt*8+nc [64], y = it [8]); 48x48 tile; wave = head.
// Blocked Q_p/K_p -> every frag load is contiguous 1KB across the wave.
// ---------------------------------------------------------------------------
__global__ __launch_bounds__(256) void k2b_qk(const u16* __restrict__ Qb,
                                              const u16* __restrict__ Kb,
                                              float* __restrict__ part) {
  const int it = blockIdx.y, jt = blockIdx.x >> 3, nc = blockIdx.x & 7;
  const int lane = threadIdx.x & 63, h = threadIdx.x >> 6;
  const int q = lane >> 4, r = lane & 15;
  const f32x4 FZ = {0.f, 0.f, 0.f, 0.f};
  f32x4 acc[3][3];
#pragma unroll
  for (int a = 0; a < 3; ++a)
#pragma unroll
    for (int b = 0; b < 3; ++b) acc[a][b] = FZ;
#pragma unroll 2
  for (int n = nc * 48; n < nc * 48 + 48; ++n) {
    const u16* Qp = Qb + (((size_t)n * 4 + h) * LL + it * 48 + r) * 32 + q * 8;
    const u16* Kp = Kb + (((size_t)n * 4 + h) * LL + jt * 48 + r) * 32 + q * 8;
    bf16x8 av[3], bv[3];
#pragma unroll
    for (int s = 0; s < 3; ++s) {
      av[s] = *(const bf16x8*)(Qp + s * 16 * 32);
      bv[s] = *(const bf16x8*)(Kp + s * 16 * 32);
    }
#pragma unroll
    for (int is = 0; is < 3; ++is)
#pragma unroll
      for (int js = 0; js < 3; ++js)
        acc[is][js] = __builtin_amdgcn_mfma_f32_16x16x32_bf16(av[is], bv[js], acc[is][js], 0, 0, 0);
  }
  float* dst = part + (size_t)(nc * 4 + h) * SZROW;
#pragma unroll
  for (int is = 0; is < 3; ++is)
#pragma unroll
    for (int js = 0; js < 3; ++js)
#pragma unroll
      for (int reg = 0; reg < 4; ++reg)
        dst[(size_t)(it * 48 + is * 16 + q * 4 + reg) * LL + jt * 48 + js * 16 + r] =
            acc[is][js][reg];
}

// ---------------------------------------------------------------------------
// K3: logits = sum of 9 partial planes; softmax over j;
// a -> bf16 blocked a_p[h][kc][i][j%32].
// ---------------------------------------------------------------------------
__global__ __launch_bounds__(384) void k3_softmax(const float* __restrict__ part,
                                                  u16* __restrict__ ap) {
  const int i = blockIdx.x, h = blockIdx.y, j = threadIdx.x;
  __shared__ float red[6];
  float l = 0.f;
#pragma unroll
  for (int c = 0; c < 9; ++c) l += part[(size_t)(c * 4 + h) * SZROW + (size_t)i * LL + j];
  float m = l;
#pragma unroll
  for (int s = 32; s >= 1; s >>= 1) m = fmaxf(m, __shfl_xor(m, s));
  const int wv = threadIdx.x >> 6;
  if ((threadIdx.x & 63) == 0) red[wv] = m;
  __syncthreads();
  m = fmaxf(fmaxf(fmaxf(red[0], red[1]), fmaxf(red[2], red[3])), fmaxf(red[4], red[5]));
  float e = __expf(l - m);
  float s = e;
#pragma unroll
  for (int t = 32; t >= 1; t >>= 1) s += __shfl_xor(s, t);
  __syncthreads();
  if ((threadIdx.x & 63) == 0) red[wv] = s;
  __syncthreads();
  s = red[0] + red[1] + red[2] + red[3] + red[4] + red[5];
  ap[(((size_t)h * 12 + (j >> 5)) * LL + i) * 32 + (j & 31)] = f2bf(e / s);
}

// ---------------------------------------------------------------------------
// K4: O[n][i][h,d] = sum_j a_h[i][j] V[n][j][h,d]; gate; @Wout + bout;
// store transposed out[i][n][:]. Grid x = n (6 ib-blocks sharing V_p[n] land
// on one XCD), y = ib. Wave = head. All PV loads contiguous-1KB; a-frags
// software-pipelined; epilogue stores routed through LDS (512B segments).
// ---------------------------------------------------------------------------
__global__ __launch_bounds__(256) void k4_out(
    const u16* __restrict__ ap, const u16* __restrict__ Vp,
    const u16* __restrict__ Gtb, const u16* __restrict__ Wot,
    const float* __restrict__ bout, float* __restrict__ out) {
  __shared__ __align__(16) char smem[64 * 132 * 4];   // go (16KB) / O (33KB) alias
  u16*   go = (u16*)smem;
  float* O  = (float*)smem;
  const int n = blockIdx.x, ib = blockIdx.y;
  const int tid = threadIdx.x;
  const int lane = tid & 63, wave = tid >> 6;
  const int h = wave;
  const int q = lane >> 4, r = lane & 15;

  // hoisted gate loads (independent of the PV loop)
  uint2 gp[4][2];
#pragma unroll
  for (int is = 0; is < 4; ++is)
#pragma unroll
    for (int ds = 0; ds < 2; ++ds) {
      int c = h * 32 + ds * 16 + r;
      gp[is][ds] =
          *(const uint2*)(Gtb + ((size_t)n * DP + c) * LL + ib * 64 + is * 16 + q * 4);
    }

  const f32x4 FZ = {0.f, 0.f, 0.f, 0.f};
  f32x4 acc[4][2];
#pragma unroll
  for (int is = 0; is < 4; ++is) { acc[is][0] = FZ; acc[is][1] = FZ; }

  const u16* Vbase = Vp + (size_t)n * 12 * (128 * 32) + (h * 32 + r) * 32 + q * 8;
  const u16* Abase = ap + ((size_t)h * 12 * LL + ib * 64 + r) * 32 + q * 8;

  bf16x8 av[2][4];   // double-buffered a-frag group
#pragma unroll
  for (int is = 0; is < 4; ++is) av[0][is] = *(const bf16x8*)(Abase + (size_t)is * 16 * 32);

#pragma unroll
  for (int halfk = 0; halfk < 2; ++halfk) {
    bf16x8 vb[6][2];
#pragma unroll
    for (int k2 = 0; k2 < 6; ++k2) {
      const u16* Vkc = Vbase + (size_t)(halfk * 6 + k2) * (128 * 32);
      vb[k2][0] = *(const bf16x8*)(Vkc);
      vb[k2][1] = *(const bf16x8*)(Vkc + 16 * 32);
    }
#pragma unroll
    for (int k2 = 0; k2 < 6; ++k2) {
      const int kc = halfk * 6 + k2;
      const int cur = kc & 1, nxt = cur ^ 1;
      if (kc < 11) {
        const u16* An = Abase + (size_t)(kc + 1) * LL * 32;
#pragma unroll
        for (int is = 0; is < 4; ++is) av[nxt][is] = *(const bf16x8*)(An + (size_t)is * 16 * 32);
      }
#pragma unroll
      for (int is = 0; is < 4; ++is) {
        acc[is][0] = __builtin_amdgcn_mfma_f32_16x16x32_bf16(av[cur][is], vb[k2][0], acc[is][0], 0, 0, 0);
        acc[is][1] = __builtin_amdgcn_mfma_f32_16x16x32_bf16(av[cur][is], vb[k2][1], acc[is][1], 0, 0, 0);
      }
    }
  }
  // gate + stash go (bf16) in swizzled LDS
#pragma unroll
  for (int is = 0; is < 4; ++is)
#pragma unroll
    for (int ds = 0; ds < 2; ++ds) {
      int c = h * 32 + ds * 16 + r;
      float g0 = bf2f((u16)(gp[is][ds].x & 0xffff)), g1 = bf2f((u16)(gp[is][ds].x >> 16));
      float g2 = bf2f((u16)(gp[is][ds].y & 0xffff)), g3 = bf2f((u16)(gp[is][ds].y >> 16));
      int il = is * 16 + q * 4;
      go[SWZ(il + 0, c)] = f2bf(g0 * acc[is][ds][0]);
      go[SWZ(il + 1, c)] = f2bf(g1 * acc[is][ds][1]);
      go[SWZ(il + 2, c)] = f2bf(g2 * acc[is][ds][2]);
      go[SWZ(il + 3, c)] = f2bf(g3 * acc[is][ds][3]);
    }
  __syncthreads();

  // out[i][co] = go[i][:] @ Wout ; D[co][i] so co is reg-contig.
  f32x4 acc2[2][4];
  wave_gemm<4>(Wot, go, wave, q, r, acc2);
  __syncthreads();   // all go reads done before O overwrites the buffer

  // stage fp32 out-tile in LDS (ld=132), then contiguous 512B-segment stores
#pragma unroll
  for (int ms = 0; ms < 2; ++ms) {
    int co = wave * 32 + ms * 16 + q * 4;
    f32x4 bo = *(const f32x4*)(bout + co);
#pragma unroll
    for (int ns = 0; ns < 4; ++ns)
      *(f32x4*)(O + (ns * 16 + r) * 132 + co) = acc2[ms][ns] + bo;
  }
  __syncthreads();
#pragma unroll
  for (int e = 0; e < 8; ++e) {
    int m = e * 256 + tid;          // 2048 16B-chunks of the 64x128 fp32 tile
    int il = m >> 5, cw = (m & 31) * 4;
    *(f32x4*)(out + ((size_t)(ib * 64 + il) * LL + n) * DP + cw) =
        *(const f32x4*)(O + il * 132 + cw);
  }
}

// ---------------------------------------------------------------------------
extern "C" void kernel_launch(void* const* d_in, const int* in_sizes, int n_in,
                              void* d_out, int out_size, void* d_ws, size_t ws_size,
                              hipStream_t stream) {
  const float* pair    = (const float*)d_in[0];
  const float* bias    = (const float*)d_in[1];
  const float* gamma_p = (const float*)d_in[2];
  const float* beta_p  = (const float*)d_in[3];
  const float* gamma_b = (const float*)d_in[4];
  const float* beta_b  = (const float*)d_in[5];
  const float* Wq      = (const float*)d_in[6];
  const float* Wk      = (const float*)d_in[7];
  const float* Wv      = (const float*)d_in[8];
  const float* Wb      = (const float*)d_in[9];
  const float* Wg      = (const float*)d_in[10];
  const float* bg      = (const float*)d_in[11];
  const float* Wout    = (const float*)d_in[12];
  const float* bout    = (const float*)d_in[13];

  // Q,K (bf16, blocked) live inside d_out (2 * L*L*128 u16 == out_size*4 B);
  // fully consumed by k2b before k4 overwrites d_out with the result.
  u16* Qb = (u16*)d_out;
  u16* Kb = Qb + (size_t)LL * LL * DP;

  char* ws = (char*)d_ws;
  const size_t BF_PLANE = (size_t)LL * LL * DP * 2;  // 37748736 B
  u16*   Vp   = (u16*)ws;
  u16*   Gtb  = (u16*)(ws + BF_PLANE);
  float* part = (float*)(ws + 2 * BF_PLANE);                     // 36 planes fp32
  u16*   ap   = (u16*)(ws + 2 * BF_PLANE + 36 * SZROW * 4);
  u16*   wbf  = (u16*)(ws + 2 * BF_PLANE + 36 * SZROW * 4 + 4 * SZROW * 2);
  float* out  = (float*)d_out;

  k_prep<<<dim3(128, 5), 128, 0, stream>>>(Wq, Wk, Wv, Wg, Wout, wbf);
  k1_ln_proj<<<dim3(6, 384), 256, 0, stream>>>(pair, gamma_p, beta_p, wbf, bg, Qb, Kb, Vp, Gtb);
  k2a_bias<<<dim3(18432), 256, 0, stream>>>(bias, gamma_b, beta_b, Wb, part);
  k2b_qk<<<dim3(64, 8), 256, 0, stream>>>(Qb, Kb, part);
  k3_softmax<<<dim3(384, 4), 384, 0, stream>>>(part, ap);
  k4_out<<<dim3(384, 6), 256, 0, stream>>>(ap, Vp, Gtb, wbf + 4 * DP * DP, bout, out);
}